// Round 3
// baseline (102.229 us; speedup 1.0000x reference)
//
#include <hip/hip_runtime.h>
#include <hip/hip_bf16.h>
#include <hip/hip_fp8.h>
#include <math.h>

typedef float floatx4 __attribute__((ext_vector_type(4)));
typedef long long i64;
typedef long long i64x2 __attribute__((ext_vector_type(2)));

#define N_ROWS 4096
#define DIM 512
#define LAM 0.5f
#define NT 64                      // 128-row block-tiles per dim (8192/128)
#define NTILES (NT * (NT + 1) / 2) // 2080 triangular tiles
#define GRID 512                   // persistent blocks: 2/CU exactly

#define GLOBAL_AS(p) ((const __attribute__((address_space(1))) void*)(p))
#define LDS_AS(p) ((__attribute__((address_space(3))) void*)(p))

__device__ __forceinline__ unsigned int pack4_fp8(float a, float b, float c, float d) {
    unsigned int u0 = __hip_cvt_float_to_fp8(a, __HIP_SATFINITE, __HIP_E4M3);
    unsigned int u1 = __hip_cvt_float_to_fp8(b, __HIP_SATFINITE, __HIP_E4M3);
    unsigned int u2 = __hip_cvt_float_to_fp8(c, __HIP_SATFINITE, __HIP_E4M3);
    unsigned int u3 = __hip_cvt_float_to_fp8(d, __HIP_SATFINITE, __HIP_E4M3);
    return u0 | (u1 << 8) | (u2 << 16) | (u3 << 24);
}

// One wave per row: L2-normalize 512 fp32 -> fp8 e4m3, stored K-PERMUTED and
// BANK-SWIZZLED. 16-B chunk ch = kt*4+q (kt: 64-k group, q: MFMA quad) holds
// k = kt*64 + {q*8..q*8+7 (lo 8B), 32+q*8..+7 (hi 8B)}; chunk is stored at
// physical position p = ch ^ (row & 7). The XOR only touches the low 3 bits,
// so each 128-B (8-chunk) group is closed under the permutation -> the GEMM
// may stage any BK multiple of 128 as a plain physical byte copy.
__global__ __launch_bounds__(256) void normalize_kernel(
    const float* __restrict__ ei, const float* __restrict__ ej,
    unsigned char* __restrict__ Z, float* __restrict__ out) {
    if (blockIdx.x == 0 && threadIdx.x == 0) out[0] = 0.0f;
    const int w = threadIdx.x >> 6, lane = threadIdx.x & 63;
    const int row = blockIdx.x * 4 + w;                     // [0, 8192)
    const float* __restrict__ src = (row < N_ROWS)
        ? (ei + (size_t)row * DIM)
        : (ej + (size_t)(row - N_ROWS) * DIM);
    const float4* src4 = (const float4*)src;
    float4 v0 = src4[lane];
    float4 v1 = src4[lane + 64];
    float s = v0.x*v0.x + v0.y*v0.y + v0.z*v0.z + v0.w*v0.w
            + v1.x*v1.x + v1.y*v1.y + v1.z*v1.z + v1.w*v1.w;
    #pragma unroll
    for (int off = 32; off; off >>= 1) s += __shfl_xor(s, off);
    const float r = rsqrtf(s);

    __shared__ __align__(16) unsigned char buf[4][512];     // k-linear fp8 rows
    ((unsigned int*)buf[w])[lane]      = pack4_fp8(v0.x*r, v0.y*r, v0.z*r, v0.w*r);
    ((unsigned int*)buf[w])[lane + 64] = pack4_fp8(v1.x*r, v1.y*r, v1.z*r, v1.w*r);
    __syncthreads();

    // full-wave permuted store: lane = kt*8 + q*2 + h, 8 B each
    const int kt = lane >> 3, q = (lane >> 1) & 3, h = lane & 1;
    i64 val = *(const i64*)(buf[w] + kt * 64 + h * 32 + q * 8);
    const int p = (kt * 4 + q) ^ (row & 7);                 // bank swizzle
    *(i64*)(Z + (size_t)row * DIM + p * 16 + h * 8) = val;
}

// Fused S = Z.Z^T (fp8 16x16x32 MFMA) + loss reduction.
// 128x128 tile, 4 waves (2x2 of 64x64), BK=128 double-buffered (64 KB LDS,
// 2 blocks/CU), persistent grid=512, continuous single-barrier pipeline.
// NEW this round (round-2 post-mortem: persistence gained only 3.6 us;
// inferred simloss ~41 us vs 17 us MFMA floor; the 2 co-resident blocks on
// each CU start together with IDENTICAL per-stage durations -> phase-locked:
// both waves of a SIMD hit vmcnt/barrier/epilogue stalls at the same instant,
// so stalls are fully exposed instead of covered by the partner wave):
//   * DE-LOCKSTEP: odd blocks sleep ~1.9K cyc at entry (~3/4 stage). The
//     offset persists (no global sync re-aligns blocks), so each wave's
//     stalls overlap the partner block's MFMA phase; setprio(1) now has a
//     partner in a different phase to win arbitration against.
//   * TAIL SPREAD: the 32 extra (5th) tiles go to bids == 0 (mod 16), not
//     bids 0-31 (consecutive bids cluster on the same CUs -> some CUs ran
//     two 5-tile blocks, +23% tail on those CUs).
__global__ __launch_bounds__(256, 2) void simloss_kernel(
    const unsigned char* __restrict__ Z, float* __restrict__ out) {
    const int tid = threadIdx.x;
    const int w = tid >> 6, lane = tid & 63;
    const int q = lane >> 4, m16 = lane & 15;
    const int wm = w & 1, wn = w >> 1;

    __shared__ __align__(16) unsigned char As[2][128 * 128];  // 16 KB per buf
    __shared__ __align__(16) unsigned char Bs[2][128 * 128];
    __shared__ float red[4];

    const int ldsOff = w * 1024;
    const int fragSwz = m16 & 7;
    // staging row/col offsets within a 128-row panel (lane-monotone copy)
    const int stRow = w * 8 + (lane >> 3);
    const int stCol = (lane & 7) * 16;

    const int bid = blockIdx.x;
    // 2080 = 512*4 + 32 extras, spread every 16th bid
    const int nMine = 4 + ((bid & 15) == 0);

    // phase-stagger odd blocks ~1920 cyc to de-lockstep CU partners
    if (bid & 1) {
        __builtin_amdgcn_s_sleep(15);   // 15*64 cyc
        __builtin_amdgcn_s_sleep(15);
    }

    // --- tile decode (float-seeded triangular index) ---
    auto decode = [](int id, int& bm, int& bn) {
        int m = (int)((2*NT + 1 - sqrtf((float)((2*NT+1)*(2*NT+1)) - 8.0f * (float)id)) * 0.5f);
        if (m < 0) m = 0; if (m > NT-1) m = NT-1;
        while ((m + 1) * NT - ((m + 1) * m) / 2 <= id) ++m;
        while (m * NT - (m * (m - 1)) / 2 > id) --m;
        bm = m;
        bn = m + (id - (m * NT - (m * (m - 1)) / 2));
    };
    // tile index for my mt-th tile: mt<4 round-robin; mt==4 -> extras block
    auto tileIdx = [bid](int mt) {
        return (mt < 4) ? (bid + mt * GRID) : (4 * GRID + (bid >> 4));
    };

    int bm, bn; decode(tileIdx(0), bm, bn);
    const unsigned char* stA = Z + (size_t)(bm * 128 + stRow) * DIM + stCol;
    const unsigned char* stB = Z + (size_t)(bn * 128 + stRow) * DIM + stCol;

    float negsum = 0.0f, possum = 0.0f;

    // issue one BK=128 stage (8 x global_load_lds width-16) into buffer par
    #define ISSUE(par, pA, pB, kOff)                                             \
        _Pragma("unroll")                                                        \
        for (int l = 0; l < 4; ++l) {                                            \
            __builtin_amdgcn_global_load_lds(GLOBAL_AS((pA) + (size_t)l * 32 * DIM + (kOff)), \
                                             LDS_AS(&As[par][ldsOff + l * 4096]), 16, 0, 0);  \
            __builtin_amdgcn_global_load_lds(GLOBAL_AS((pB) + (size_t)l * 32 * DIM + (kOff)), \
                                             LDS_AS(&Bs[par][ldsOff + l * 4096]), 16, 0, 0);  \
        }

    // prologue: tile 0, stage 0 -> buf 0
    ISSUE(0, stA, stB, 0)

    for (int mt = 0; mt < nMine; ++mt) {
        const int tm = bm * 2 + wm, tn = bn * 2 + wn;
        // decode the NEXT tile early (VALU, hides under compute)
        const bool hasNext = (mt + 1 < nMine);
        int nbm = 0, nbn = 0;
        const unsigned char *nA = stA, *nB = stB;
        if (hasNext) {
            decode(tileIdx(mt + 1), nbm, nbn);
            nA = Z + (size_t)(nbm * 128 + stRow) * DIM + stCol;
            nB = Z + (size_t)(nbn * 128 + stRow) * DIM + stCol;
        }

        floatx4 acc[4][4] = {};

        #pragma unroll
        for (int s = 0; s < 4; ++s) {
            const int par = (mt * 4 + s) & 1;          // buffer parity (continuous)
            // wait for THIS stage's 8 loads (nothing newer in flight:
            // next stage is issued after the barrier below)
            asm volatile("s_waitcnt vmcnt(0)" ::: "memory");
            __builtin_amdgcn_sched_barrier(0);
            __builtin_amdgcn_s_barrier();              // readers of buf[par^1] done
            // issue stage g+1 into buf[par^1]
            if (s < 3)        { ISSUE(par ^ 1, stA, stB, (s + 1) * 128) }
            else if (hasNext) { ISSUE(par ^ 1, nA, nB, 0) }

            const unsigned char* fraA = &As[par][(wm * 64 + m16) * 128];
            const unsigned char* fraB = &Bs[par][(wn * 64 + m16) * 128];
            #pragma unroll
            for (int g = 0; g < 2; ++g) {              // two K=64 groups
                const int cOff = ((g * 4 + q) ^ fragSwz) << 4;
                i64x2 af[4], bf[4];
                #pragma unroll
                for (int i = 0; i < 4; ++i) af[i] = *(const i64x2*)(fraA + i * 16 * 128 + cOff);
                #pragma unroll
                for (int j = 0; j < 4; ++j) bf[j] = *(const i64x2*)(fraB + j * 16 * 128 + cOff);
                __builtin_amdgcn_s_setprio(1);
                #pragma unroll
                for (int i = 0; i < 4; ++i)
                    #pragma unroll
                    for (int j = 0; j < 4; ++j) {
                        acc[i][j] = __builtin_amdgcn_mfma_f32_16x16x32_fp8_fp8(af[i].x, bf[j].x, acc[i][j], 0, 0, 0);
                        acc[i][j] = __builtin_amdgcn_mfma_f32_16x16x32_fp8_fp8(af[i].y, bf[j].y, acc[i][j], 0, 0, 0);
                    }
                __builtin_amdgcn_s_setprio(0);
            }
        }

        // --- per-tile epilogue (no barriers; next tile's loads in flight) ---
        // C/D map: row = i*16 + q*4 + r, col = j*16 + m16 (tile-local)
        const float wgt = (tn < tm) ? 0.0f : ((tm == tn) ? 1.0f : 2.0f);
        const bool hasPos = (tn == tm + 64);           // wave-uniform
        if (wgt != 0.0f) {
            const int rowBase = tm * 64 + q * 4;
            const int colBase = tn * 64 + m16;
            float nacc = 0.0f;
            #pragma unroll
            for (int j = 0; j < 4; ++j) {
                const int cg = colBase + j * 16;
                float p = 1.0f;
                #pragma unroll
                for (int i = 0; i < 4; ++i) {
                    const int rg0 = rowBase + i * 16;
                    #pragma unroll
                    for (int r = 0; r < 4; ++r) {
                        const float sv = acc[i][j][r];
                        float e = __expf(sv - LAM);
                        if (rg0 + r == cg) e = 0.0f;   // mask main diagonal
                        p *= (1.0f + e);
                        if (hasPos && cg == rg0 + r + N_ROWS)  // positive pair
                            possum += log1pf(expf(-sv + LAM));
                    }
                }
                nacc += __logf(p);
            }
            negsum += nacc * wgt;
        }

        bm = nbm; bn = nbn; stA = nA; stB = nB;
    }

    // --- block reduction: one atomic per block ---
    #pragma unroll
    for (int off = 32; off; off >>= 1) {
        negsum += __shfl_xor(negsum, off);
        possum += __shfl_xor(possum, off);
    }
    const float part = negsum * (1.0f / (12.0f * (float)N_ROWS))
                     + possum * (1.0f / (float)N_ROWS);
    if (lane == 0) red[w] = part;
    __syncthreads();
    if (tid == 0) atomicAdd(out, red[0] + red[1] + red[2] + red[3]);
    #undef ISSUE
}

extern "C" void kernel_launch(void* const* d_in, const int* in_sizes, int n_in,
                              void* d_out, int out_size, void* d_ws, size_t ws_size,
                              hipStream_t stream) {
    const float* ei = (const float*)d_in[0];
    const float* ej = (const float*)d_in[1];
    float* out = (float*)d_out;
    unsigned char* Z = (unsigned char*)d_ws;  // 8192*512 fp8 = 4 MB scratch

    normalize_kernel<<<2048, 256, 0, stream>>>(ei, ej, Z, out);
    simloss_kernel<<<GRID, 256, 0, stream>>>(Z, out);
}

// Round 4
// 101.345 us; speedup vs baseline: 1.0087x; 1.0087x over previous
//
#include <hip/hip_runtime.h>
#include <hip/hip_bf16.h>
#include <hip/hip_fp8.h>
#include <math.h>

typedef float floatx4 __attribute__((ext_vector_type(4)));
typedef long long i64;
typedef long long i64x2 __attribute__((ext_vector_type(2)));

#define N_ROWS 4096
#define DIM 512
#define LAM 0.5f
#define NT 64                      // 128-row block-tiles per dim (8192/128)
#define NTILES (NT * (NT + 1) / 2) // 2080 triangular tiles
#define GRID 512                   // persistent blocks: 2/CU exactly

#define GLOBAL_AS(p) ((const __attribute__((address_space(1))) void*)(p))
#define LDS_AS(p) ((__attribute__((address_space(3))) void*)(p))

__device__ __forceinline__ unsigned int pack4_fp8(float a, float b, float c, float d) {
    unsigned int u0 = __hip_cvt_float_to_fp8(a, __HIP_SATFINITE, __HIP_E4M3);
    unsigned int u1 = __hip_cvt_float_to_fp8(b, __HIP_SATFINITE, __HIP_E4M3);
    unsigned int u2 = __hip_cvt_float_to_fp8(c, __HIP_SATFINITE, __HIP_E4M3);
    unsigned int u3 = __hip_cvt_float_to_fp8(d, __HIP_SATFINITE, __HIP_E4M3);
    return u0 | (u1 << 8) | (u2 << 16) | (u3 << 24);
}

// One wave per row: L2-normalize 512 fp32 -> fp8 e4m3, stored K-PERMUTED and
// BANK-SWIZZLED. 16-B chunk ch = kt*4+q (kt: 64-k group, q: MFMA quad) holds
// k = kt*64 + {q*8..q*8+7 (lo 8B), 32+q*8..+7 (hi 8B)}; chunk is stored at
// physical position p = ch ^ (row & 7). The XOR only touches the low 3 bits,
// so each 128-B (8-chunk) group is closed under the permutation -> the GEMM
// may stage any BK multiple of 128 as a plain physical byte copy.
__global__ __launch_bounds__(256) void normalize_kernel(
    const float* __restrict__ ei, const float* __restrict__ ej,
    unsigned char* __restrict__ Z, float* __restrict__ out) {
    if (blockIdx.x == 0 && threadIdx.x == 0) out[0] = 0.0f;
    const int w = threadIdx.x >> 6, lane = threadIdx.x & 63;
    const int row = blockIdx.x * 4 + w;                     // [0, 8192)
    const float* __restrict__ src = (row < N_ROWS)
        ? (ei + (size_t)row * DIM)
        : (ej + (size_t)(row - N_ROWS) * DIM);
    const float4* src4 = (const float4*)src;
    float4 v0 = src4[lane];
    float4 v1 = src4[lane + 64];
    float s = v0.x*v0.x + v0.y*v0.y + v0.z*v0.z + v0.w*v0.w
            + v1.x*v1.x + v1.y*v1.y + v1.z*v1.z + v1.w*v1.w;
    #pragma unroll
    for (int off = 32; off; off >>= 1) s += __shfl_xor(s, off);
    const float r = rsqrtf(s);

    __shared__ __align__(16) unsigned char buf[4][512];     // k-linear fp8 rows
    ((unsigned int*)buf[w])[lane]      = pack4_fp8(v0.x*r, v0.y*r, v0.z*r, v0.w*r);
    ((unsigned int*)buf[w])[lane + 64] = pack4_fp8(v1.x*r, v1.y*r, v1.z*r, v1.w*r);
    __syncthreads();

    // full-wave permuted store: lane = kt*8 + q*2 + h, 8 B each
    const int kt = lane >> 3, q = (lane >> 1) & 3, h = lane & 1;
    i64 val = *(const i64*)(buf[w] + kt * 64 + h * 32 + q * 8);
    const int p = (kt * 4 + q) ^ (row & 7);                 // bank swizzle
    *(i64*)(Z + (size_t)row * DIM + p * 16 + h * 8) = val;
}

// Fused S = Z.Z^T (fp8 16x16x32 MFMA) + loss reduction.
// 128x128 tile, 4 waves (2x2 of 64x64), BK=128 double-buffered (64 KB LDS,
// 2 blocks/CU), persistent grid=512, continuous single-barrier pipeline.
// Round-3 post-mortem: de-lockstep sleep was NEUTRAL->slightly harmful
// (phase-lock theory falsified) -> removed. Tail spread kept.
// NEW this round: the inner loop previously issued, for each (i,j),
//   acc[i][j] = mfma(af.x, bf.x, acc[i][j]);
//   acc[i][j] = mfma(af.y, bf.y, acc[i][j]);   // depends on the PREVIOUS inst
// i.e. every 2nd MFMA was result-dependent on its immediate predecessor. If
// emitted in that order, the wave eats the MFMA result latency every pair;
// with only 2 waves/SIMD the pipe cannot fill from the partner. Restructured
// into an x-PASS (16 independent MFMAs) then a y-PASS (dependency distance
// 16). Accumulation order per acc[i][j] is unchanged (x then y) -> bitwise
// identical result.
__global__ __launch_bounds__(256, 2) void simloss_kernel(
    const unsigned char* __restrict__ Z, float* __restrict__ out) {
    const int tid = threadIdx.x;
    const int w = tid >> 6, lane = tid & 63;
    const int q = lane >> 4, m16 = lane & 15;
    const int wm = w & 1, wn = w >> 1;

    __shared__ __align__(16) unsigned char As[2][128 * 128];  // 16 KB per buf
    __shared__ __align__(16) unsigned char Bs[2][128 * 128];
    __shared__ float red[4];

    const int ldsOff = w * 1024;
    const int fragSwz = m16 & 7;
    // staging row/col offsets within a 128-row panel (lane-monotone copy)
    const int stRow = w * 8 + (lane >> 3);
    const int stCol = (lane & 7) * 16;

    const int bid = blockIdx.x;
    // 2080 = 512*4 + 32 extras, spread every 16th bid
    const int nMine = 4 + ((bid & 15) == 0);

    // --- tile decode (float-seeded triangular index) ---
    auto decode = [](int id, int& bm, int& bn) {
        int m = (int)((2*NT + 1 - sqrtf((float)((2*NT+1)*(2*NT+1)) - 8.0f * (float)id)) * 0.5f);
        if (m < 0) m = 0; if (m > NT-1) m = NT-1;
        while ((m + 1) * NT - ((m + 1) * m) / 2 <= id) ++m;
        while (m * NT - (m * (m - 1)) / 2 > id) --m;
        bm = m;
        bn = m + (id - (m * NT - (m * (m - 1)) / 2));
    };
    // tile index for my mt-th tile: mt<4 round-robin; mt==4 -> extras block
    auto tileIdx = [bid](int mt) {
        return (mt < 4) ? (bid + mt * GRID) : (4 * GRID + (bid >> 4));
    };

    int bm, bn; decode(tileIdx(0), bm, bn);
    const unsigned char* stA = Z + (size_t)(bm * 128 + stRow) * DIM + stCol;
    const unsigned char* stB = Z + (size_t)(bn * 128 + stRow) * DIM + stCol;

    float negsum = 0.0f, possum = 0.0f;

    // issue one BK=128 stage (8 x global_load_lds width-16) into buffer par
    #define ISSUE(par, pA, pB, kOff)                                             \
        _Pragma("unroll")                                                        \
        for (int l = 0; l < 4; ++l) {                                            \
            __builtin_amdgcn_global_load_lds(GLOBAL_AS((pA) + (size_t)l * 32 * DIM + (kOff)), \
                                             LDS_AS(&As[par][ldsOff + l * 4096]), 16, 0, 0);  \
            __builtin_amdgcn_global_load_lds(GLOBAL_AS((pB) + (size_t)l * 32 * DIM + (kOff)), \
                                             LDS_AS(&Bs[par][ldsOff + l * 4096]), 16, 0, 0);  \
        }

    // prologue: tile 0, stage 0 -> buf 0
    ISSUE(0, stA, stB, 0)

    for (int mt = 0; mt < nMine; ++mt) {
        const int tm = bm * 2 + wm, tn = bn * 2 + wn;
        // decode the NEXT tile early (VALU, hides under compute)
        const bool hasNext = (mt + 1 < nMine);
        int nbm = 0, nbn = 0;
        const unsigned char *nA = stA, *nB = stB;
        if (hasNext) {
            decode(tileIdx(mt + 1), nbm, nbn);
            nA = Z + (size_t)(nbm * 128 + stRow) * DIM + stCol;
            nB = Z + (size_t)(nbn * 128 + stRow) * DIM + stCol;
        }

        floatx4 acc[4][4] = {};

        #pragma unroll
        for (int s = 0; s < 4; ++s) {
            const int par = (mt * 4 + s) & 1;          // buffer parity (continuous)
            // wait for THIS stage's 8 loads (nothing newer in flight:
            // next stage is issued after the barrier below)
            asm volatile("s_waitcnt vmcnt(0)" ::: "memory");
            __builtin_amdgcn_sched_barrier(0);
            __builtin_amdgcn_s_barrier();              // readers of buf[par^1] done
            // issue stage g+1 into buf[par^1]
            if (s < 3)        { ISSUE(par ^ 1, stA, stB, (s + 1) * 128) }
            else if (hasNext) { ISSUE(par ^ 1, nA, nB, 0) }

            const unsigned char* fraA = &As[par][(wm * 64 + m16) * 128];
            const unsigned char* fraB = &Bs[par][(wn * 64 + m16) * 128];
            #pragma unroll
            for (int g = 0; g < 2; ++g) {              // two K=64 groups
                const int cOff = ((g * 4 + q) ^ fragSwz) << 4;
                i64x2 af[4], bf[4];
                #pragma unroll
                for (int i = 0; i < 4; ++i) af[i] = *(const i64x2*)(fraA + i * 16 * 128 + cOff);
                #pragma unroll
                for (int j = 0; j < 4; ++j) bf[j] = *(const i64x2*)(fraB + j * 16 * 128 + cOff);
                __builtin_amdgcn_s_setprio(1);
                // x-pass: 16 independent MFMAs
                #pragma unroll
                for (int i = 0; i < 4; ++i)
                    #pragma unroll
                    for (int j = 0; j < 4; ++j)
                        acc[i][j] = __builtin_amdgcn_mfma_f32_16x16x32_fp8_fp8(af[i].x, bf[j].x, acc[i][j], 0, 0, 0);
                // y-pass: each MFMA's dependency is 16 instructions away
                #pragma unroll
                for (int i = 0; i < 4; ++i)
                    #pragma unroll
                    for (int j = 0; j < 4; ++j)
                        acc[i][j] = __builtin_amdgcn_mfma_f32_16x16x32_fp8_fp8(af[i].y, bf[j].y, acc[i][j], 0, 0, 0);
                __builtin_amdgcn_s_setprio(0);
            }
        }

        // --- per-tile epilogue (no barriers; next tile's loads in flight) ---
        // C/D map: row = i*16 + q*4 + r, col = j*16 + m16 (tile-local)
        const float wgt = (tn < tm) ? 0.0f : ((tm == tn) ? 1.0f : 2.0f);
        const bool hasPos = (tn == tm + 64);           // wave-uniform
        if (wgt != 0.0f) {
            const int rowBase = tm * 64 + q * 4;
            const int colBase = tn * 64 + m16;
            float nacc = 0.0f;
            #pragma unroll
            for (int j = 0; j < 4; ++j) {
                const int cg = colBase + j * 16;
                float p = 1.0f;
                #pragma unroll
                for (int i = 0; i < 4; ++i) {
                    const int rg0 = rowBase + i * 16;
                    #pragma unroll
                    for (int r = 0; r < 4; ++r) {
                        const float sv = acc[i][j][r];
                        float e = __expf(sv - LAM);
                        if (rg0 + r == cg) e = 0.0f;   // mask main diagonal
                        p *= (1.0f + e);
                        if (hasPos && cg == rg0 + r + N_ROWS)  // positive pair
                            possum += log1pf(expf(-sv + LAM));
                    }
                }
                nacc += __logf(p);
            }
            negsum += nacc * wgt;
        }

        bm = nbm; bn = nbn; stA = nA; stB = nB;
    }

    // --- block reduction: one atomic per block ---
    #pragma unroll
    for (int off = 32; off; off >>= 1) {
        negsum += __shfl_xor(negsum, off);
        possum += __shfl_xor(possum, off);
    }
    const float part = negsum * (1.0f / (12.0f * (float)N_ROWS))
                     + possum * (1.0f / (float)N_ROWS);
    if (lane == 0) red[w] = part;
    __syncthreads();
    if (tid == 0) atomicAdd(out, red[0] + red[1] + red[2] + red[3]);
    #undef ISSUE
}

extern "C" void kernel_launch(void* const* d_in, const int* in_sizes, int n_in,
                              void* d_out, int out_size, void* d_ws, size_t ws_size,
                              hipStream_t stream) {
    const float* ei = (const float*)d_in[0];
    const float* ej = (const float*)d_in[1];
    float* out = (float*)d_out;
    unsigned char* Z = (unsigned char*)d_ws;  // 8192*512 fp8 = 4 MB scratch

    normalize_kernel<<<2048, 256, 0, stream>>>(ei, ej, Z, out);
    simloss_kernel<<<GRID, 256, 0, stream>>>(Z, out);
}